// Round 4
// baseline (1002.306 us; speedup 1.0000x reference)
//
#include <hip/hip_runtime.h>
#include <hip/hip_bf16.h>

using u16 = unsigned short;
using u32 = unsigned int;

typedef __bf16 bf16x8 __attribute__((ext_vector_type(8)));
typedef float f32x4 __attribute__((ext_vector_type(4)));
typedef float f32x4v __attribute__((ext_vector_type(4)));
typedef unsigned short u16x8 __attribute__((ext_vector_type(8)));

constexpr int NT  = 8192;   // B*T tokens
constexpr int DIM = 1024;
constexpr int FF  = 4096;
constexpr int NE  = 8;      // experts

constexpr int BM2 = 256, BN2 = 256, BK2 = 64;
constexpr int MAXMB = 72;               // max 256-row m-blocks: 16384/256 + 8
constexpr int G1X = MAXMB * (FF / BN2);   // 72*16 = 1152 (%8==0)
constexpr int G2X = MAXMB * (DIM / BN2);  // 72*4  = 288  (%8==0)

__device__ inline u16 f2bf(float f) {
    u32 u = __float_as_uint(f);
    u32 r = (u + 0x7fffu + ((u >> 16) & 1u)) >> 16;
    return (u16)r;
}

// direct global->LDS, 16B per lane, wave-uniform LDS base + lane*16
__device__ inline void gload16(const void* g, void* l) {
    __builtin_amdgcn_global_lo\
ad_lds(
        (const __attribute__((address_space(1))) void*)g,
        (__attribute__((address_space(3))) void*)l, 16, 0, 0);
}

// ---------------- router: logits -> top2 -> softmax weights ----------------
__global__ __launch_bounds__(256) void k_router(const float* __restrict__ x,
                                                const float* __restrict__ Wr,
                                                int* __restrict__ topi,
                                                float* __restrict__ topw,
                                                int* __restrict__ counts) {
    int w = threadIdx.x >> 6, lane = threadIdx.x & 63;
    int t = blockIdx.x * 4 + w;
    const float* xt = x + (size_t)t * DIM;
    float acc[NE];
#pragma unroll
    for (int e = 0; e < NE; e++) acc[e] = 0.f;
    for (int i = 0; i < DIM / 64; i++) {
        int d = i * 64 + lane;
        float xv = xt[d];
#pragma unroll
        for (int e = 0; e < NE; e++) acc[e] += xv * Wr[e * DIM + d];
    }
#pragma unroll
    for (int e = 0; e < NE; e++) {
#pragma unroll
        for (int off = 32; off >= 1; off >>= 1) acc[e] += __shfl_xor(acc[e], off, 64);
    }
    if (lane == 0) {
        int b0 = 0; float v0 = acc[0];
        for (int e = 1; e < NE; e++) if (acc[e] > v0) { v0 = acc[e]; b0 = e; }
        int b1 = -1; float v1 = -INFINITY;
        for (int e = 0; e < NE; e++) if (e != b0 && acc[e] > v1) { v1 = acc[e]; b1 = e; }
        float e1 = __expf(v1 - v0);
        float w0 = 1.f / (1.f + e1);
        topi[t * 2] = b0; topi[t * 2 + 1] = b1;
        topw[t * 2] = w0; topw[t * 2 + 1] = 1.f - w0;
        atomicAdd(&counts[b0], 1);
        atomicAdd(&counts[b1], 1);
    }
}

// prefix + 256-row m-block table for grid compaction
__global__ void k_prefix(const int* __restrict__ counts, int* __restrict__ offs,
                         int* __restrict__ cursor, int* __restrict__ tblE,
                         int* __restrict__ tblM, int* __restrict__ nmb) {
    if (threadIdx.x == 0) {
        int s = 0, idx = 0;
        for (int e = 0; e < NE; e++) {
            offs[e] = s; cursor[e] = s;
            int nb = (counts[e] + BM2 - 1) / BM2;
            for (int b = 0; b < nb; b++) { tblE[idx] = e; tblM[idx] = b * BM2; idx++; }
            s += counts[e];
        }
        *nmb = idx;
    }
}

__global__ __launch_bounds__(256) void k_build(const int* __restrict__ topi,
                                               const float* __restrict__ topw,
                                               int* __restrict__ cursor,
                                               int* __restrict__ rows,
                                               float* __restrict__ roww) {
    int t = blockIdx.x * 256 + threadIdx.x;
    if (t >= NT) return;
#pragma unroll
    for (int s = 0; s < 2; s++) {
        int e = topi[t * 2 + s];
        int p = atomicAdd(&cursor[e], 1);
        rows[p] = t * 2 + s;
        roww[p] = topw[t * 2 + s];
    }
}

// ---------------- fp32 -> bf16 convert (x) ----------------
__global__ __launch_bounds__(256) void k_cvt(const float* __restrict__ in,
                                             u16* __restrict__ out, int n) {
    int i = blockIdx.x * 256 + threadIdx.x;
    int base = i * 8;
    if (base >= n) return;
    const f32x4v* in4 = reinterpret_cast<const f32x4v*>(in + base);
    f32x4v a = in4[0], b = in4[1];
    u16x8 o;
#pragma unroll
    for (int j = 0; j < 4; j++) { o[j] = f2bf(a[j]); o[j + 4] = f2bf(b[j]); }
    *reinterpret_cast<u16x8*>(out + base) = o;
}

// ---------------- transpose + convert: in [R][C] fp32 -> out [C][R] bf16 ----------------
__global__ __launch_bounds__(256) void k_tcvt(const float* __restrict__ in,
                                              u16* __restrict__ out, int R, int C) {
    __shared__ float tile[64][65];
    int e = blockIdx.z;
    const float* pin = in + (size_t)e * R * C;
    u16* pout = out + (size_t)e * R * C;
    int c0 = blockIdx.x * 64, r0 = blockIdx.y * 64;
    int t = threadIdx.x;
    int lc = (t & 15) * 4, lr = t >> 4;
#pragma unroll
    for (int i = 0; i < 4; i++) {
        int r = lr + i * 16;
        f32x4v v = *reinterpret_cast<const f32x4v*>(&pin[(size_t)(r0 + r) * C + c0 + lc]);
        tile[r][lc] = v[0]; tile[r][lc + 1] = v[1];
        tile[r][lc + 2] = v[2]; tile[r][lc + 3] = v[3];
    }
    __syncthreads();
    int oc = (t & 7) * 8;
    int orow = t >> 3;
#pragma unroll
    for (int i = 0; i < 2; i++) {
        int cc = orow + i * 32;
        u16x8 o;
#pragma unroll
        for (int j = 0; j < 8; j++) o[j] = f2bf(tile[oc + j][cc]);
        *reinterpret_cast<u16x8*>(&pout[(size_t)(c0 + cc) * R + r0 + oc]) = o;
    }
}

// ======== shared 256x256x64 phase-interleaved GEMM machinery (macros) ========
// LDS per buffer: A[256][64] bf16 swizzled (chunk c: row=c>>3, col-chunk=(c&7)^(row&7))
// frag read: elem = row*64 + ((kk*4+(lane>>4)) ^ (lane&7))*8   (row&7 == lane&7)

#define STAGEK(cur, kt) do { \
    _Pragma("unroll") for (int j_ = 0; j_ < 4; j_++) \
        gload16(aS[j_] + (kt) * BK2, &As[cur][(j_ * 512 + wid * 64) * 8]); \
    _Pragma("unroll") for (int j_ = 0; j_ < 4; j_++) \
        gload16(bS[j_] + (kt) * BK2, &Bs[cur][(j_ * 512 + wid * 64) * 8]); \
} while (0)

#define PHB(cur) do { \
    _Pragma("unroll") for (int kk_ = 0; kk_ < 2; kk_++) \
    _Pragma("unroll") for (int n_ = 0; n_ < 4; n_++) { \
        int row_ = wn * 64 + n_ * 16 + (lane & 15); \
        bfr[kk_][n_] = *reinterpret_cast<const bf16x8*>( \
            &Bs[cur][row_ * 64 + ((kk_ * 4 + (lane >> 4)) ^ (lane & 7)) * 8]); } \
} while (0)

#define PHA(cur, q) do { \
    _Pragma("unroll") for (int kk_ = 0; kk_ < 2; kk_++) \
    _Pragma("unroll") for (int m_ = 0; m_ < 2; m_++) { \
        int row_ = wm * 128 + ((q) * 2 + m_) * 16 + (lane & 15); \
        af[kk_][m_] = *reinterpret_cast<const bf16x8*>( \
            &As[cur][row_ * 64 + ((kk_ * 4 + (lane >> 4)) ^ (lane & 7)) * 8]); } \
} while (0)

#define PHMFMA(q) do { \
    __builtin_amdgcn_s_barrier(); \
    asm volatile("s_waitcnt lgkmcnt(0)" ::: "memory"); \
    __builtin_amdgcn_sched_barrier(0); \
    __builtin_amdgcn_s_setprio(1); \
    _Pragma("unroll") for (int kk_ = 0; kk_ < 2; kk_++) \
    _Pragma("unroll") for (int m_ = 0; m_ < 2; m_++) \
    _Pragma("unroll") for (int n_ = 0; n_ < 4; n_++) \
        acc[(q) * 2 + m_][n_] = __builtin_amdgcn_mfma_f32_16x16x32_bf16( \
            af[kk_][m_], bfr[kk_][n_], acc[(q) * 2 + m_][n_], 0, 0, 0); \
    __builtin_amdgcn_s_setprio(0); \
    __builtin_amdgcn_s_barrier(); \
} while (0)

// boundary: buf[cur] fully consumed (all reads retired before last barrier);
// stage tile t+2 into it, then drain tile t+1's loads (vmcnt counted, never 0
// until the final boundary), then barrier so ALL waves' shares are visible.
#define TILE(cur, t, NKT) do { \
    bf16x8 bfr[2][4]; bf16x8 af[2][2]; \
    PHB(cur); PHA(cur, 0); PHMFMA(0); \
    PHA(cur, 1); PHMFMA(1); \
    PHA(cur, 2); PHMFMA(2); \
    PHA(cur, 3); PHMFMA(3); \
    if ((t) + 1 < (NKT)) { \
        if ((t) + 2 < (NKT)) { \
            STAGEK(cur, (t) + 2); \
            asm volatile("s_waitcnt vmcnt(8)" ::: "memory"); \
        } else { \
            asm volatile("s_waitcnt vmcnt(0)" ::: "memory"); \
        } \
        __builtin_amdgcn_s_barrier(); \
    } \
} while (0)

// ---------------- GEMM1: H = gelu(x @ W1[e]) ----------------
__global__ __launch_bounds__(512, 2) void k_gemm1(const u16* __restrict__ xbf,
                                                  const u16* __restrict__ w1t, // [E][FF][DIM]
                                                  const int* __restrict__ rows,
                                                  const int* __restrict__ offs,
                                                  const int* __restrict__ counts,
                                                  const int* __restrict__ tblE,
                                                  const int* __restrict__ tblM,
                                                  const int* __restrict__ nmb,
                                                  u16* __restrict__ H) {
    __shared__ __align__(16) u16 As[2][BM2 * BK2];
    __shared__ __align__(16) u16 Bs[2][BN2 * BK2];

    int bid = blockIdx.x;
    int l = (bid & 7) * (G1X >> 3) + (bid >> 3);   // XCD-bijective
    int yn = l / MAXMB, xm = l % MAXMB;            // xm inner: B-panel L2-hot
    if (xm >= *nmb) return;
    int e = tblE[xm], m0 = tblM[xm];
    int cnt = counts[e], off = offs[e];
    int n0 = yn * BN2;

    int tid = threadIdx.x, lane = tid & 63, wid = tid >> 6;
    int wm = wid >> 2, wn = wid & 3;

    f32x4 acc[8][4];
#pragma unroll
    for (int i = 0; i < 8; i++)
#pragma unroll
        for (int j = 0; j < 4; j++) acc[i][j] = (f32x4)(0.f);

    const u16* aS[4]; const u16* bS[4];
#pragma unroll
    for (int j = 0; j < 4; j++) {
        int c = j * 512 + tid;
        int row = c >> 3, sg = (c & 7) ^ (row & 7);
        int lrow = m0 + row;
        int tok = (lrow < cnt) ? (rows[off + lrow] >> 1) : 0;
        aS[j] = xbf + (size_t)tok * DIM + sg * 8;
        bS[j] = w1t + (size_t)e * FF * DIM + (size_t)(n0 + row) * DIM + sg * 8;
    }

    constexpr int NKT = DIM / BK2;  // 16
    STAGEK(0, 0);
    STAGEK(1, 1);
    asm volatile("s_waitcnt vmcnt(8)" ::: "memory");
    __builtin_amdgcn_s_barrier();
#pragma unroll 1
    for (int t = 0; t < NKT; t += 2) {
        TILE(0, t, NKT);
        TILE(1, t + 1, NKT);
    }

    // epilogue: exact GELU -> bf16 H
#pragma unroll
    for (int mi = 0; mi < 8; mi++) {
#pragma unroll
        for (int r = 0; r < 4; r++) {
            int lrow = m0 + wm * 128 + mi * 16 + ((lane >> 4) << 2) + r;
            if (lrow >= cnt) continue;
            u16* hp = H + (size_t)(off + lrow) * FF + n0 + wn * 64;
#pragma unroll
            for (int nj = 0; nj < 4; nj++) {
                float v = acc[mi][nj][r];
                v = 0.5f * v * (1.f + erff(v * 0.70710678118f));
                hp[nj * 16 + (lane & 15)] = f2bf(v);
            }
        }
    }
}

// ---------------- GEMM2: out[token] += w * (H[row] @ W2[e]) ----------------
__global__ __launch_bounds__(512, 2) void k_gemm2(const u16* __restrict__ H,
                                                  const u16* __restrict__ w2t, // [E][DIM][FF]
                                                  const int* __restrict__ rows,
                                                  const float* __restrict__ roww,
                                                  const int* __restrict__ offs,
                                                  const int* __restrict__ counts,
                                                  const int* __restrict__ tblE,
                                                  const int* __restrict__ tblM,
                                                  const int* __restrict__ nmb,
                                                  float* __restrict__ out) {
    __shared__ __align__(16) u16 As[2][BM2 * BK2];
    __shared__ __align__(16) u16 Bs[2][BN2 * BK2];

    int bid = blockIdx.x;
    int l = (bid & 7) * (G2X >> 3) + (bid >> 3);
    int yn = l / MAXMB, xm = l % MAXMB;
    if (xm >= *nmb) return;
    int e = tblE[xm], m0 = tblM[xm];
    int cnt = counts[e], off = offs[e];
    int n0 = yn * BN2;

    int tid = threadIdx.x, lane = tid & 63, wid = tid >> 6;
    int wm = wid >> 2, wn = wid & 3;

    f32x4 acc[8][4];
#pragma unroll
    for (int i = 0; i < 8; i++)
#pragma unroll
        for (int j = 0; j < 4; j++) acc[i][j] = (f32x4)(0.f);

    const u16* aS[4]; const u16* bS[4];
#pragma unroll
    for (int j = 0; j < 4; j++) {
        int c = j * 512 + tid;
        int row = c >> 3, sg = (c & 7) ^ (row & 7);
        int lrow = m0 + row;
        int grow = off + ((lrow < cnt) ? lrow : (cnt - 1));
        aS[j] = H + (size_t)grow * FF + sg * 8;
        bS[j] = w2t + (size_t)e * DIM * FF + (size_t)(n0 + row) * FF + sg * 8;
    }

    constexpr int NKT = FF / BK2;  // 64
    STAGEK(0, 0);
    STAGEK(1, 1);
    asm volatile("s_waitcnt vmcnt(8)" ::: "memory");
    __builtin_amdgcn_s_barrier();
#pragma unroll 1
    for (int t = 0; t < NKT; t += 2) {
        TILE(0, t, NKT);
        TILE(1, t + 1, NKT);
    }

#pragma unroll
    for (int mi = 0; mi < 8; mi++) {
#pragma unroll
        for (int r = 0; r < 4; r++) {
            int lrow = m0 + wm * 128 + mi * 16 + ((lane >> 4) << 2) + r;
            if (lrow >= cnt) continue;
            int rv = rows[off + lrow];
            float wgt = roww[off + lrow];
            float* op = out + (size_t)(rv >> 1) * DIM + n0 + wn * 64;
#pragma unroll
            for (int nj = 0; nj < 4; nj++)
                atomicAdd(&op[nj * 16 + (lane & 15)], wgt * acc[mi][nj][r]);
        }
    }
}

extern "C" void kernel_launch(void* const* d_in, const int* in_sizes, int n_in,
                              void* d_out, int out_size, void* d_ws, size_t ws_size,
                              hipStream_t stream) {
    const float* x  = (const float*)d_in[0];
    const float* Wr = (const float*)d_in[1];
    const float* W1 = (const float*)d_in[2];
    const float* W2 = (const float*)d_in[3];
    float* out = (float*)d_out;

    char* w = (char*)d_ws;
    size_t o = 0;
    auto carve = [&](size_t bytes) -> void* {
        void* p = w + o;
        o = (o + bytes + 255) & ~(size_t)255;
        return p;
    };
    int*   counts = (int*)carve(NE * 4);
    int*   offs   = (int*)carve(NE * 4);
    int*   cursor = (int*)carve(NE * 4);
    int*   tblE   = (int*)carve(MAXMB * 4);
    int*   tblM   = (int*)carve(MAXMB * 4);
    int*   nmb    = (int*)carve(4);
    int*   topi   = (int*)carve((size_t)NT * 2 * 4);
    float* topw   = (float*)carve((size_t)NT * 2 * 4);
    int*   rows   = (int*)carve((size_t)NT * 2 * 4);
    float* roww   = (float*)carve((size_t)NT * 2 * 4);
    u16*   xbf    = (u16*)carve((size_t)NT * DIM * 2);
    u16*   w1t    = (u16*)carve((size_t)NE * DIM * FF * 2);
    u16*   w2t    = (u16*)carve((size_t)NE * DIM * FF * 2);
    u16*   Hbuf   = (u16*)carve((size_t)NT * 2 * FF * 2);
    (void)ws_size; (void)in_sizes; (void)n_in; (void)out_size;

    hipMemsetAsync(counts, 0, NE * 4, stream);
    hipMemsetAsync(d_out, 0, (size_t)NT * DIM * 4, stream);

    k_router<<<NT / 4, 256, 0, stream>>>(x, Wr, topi, topw, counts);
    k_prefix<<<1, 64, 0, stream>>>(counts, offs, cursor, tblE, tblM, nmb);
    k_build<<<NT / 256, 256, 0, stream>>>(topi, topw, cursor, rows, roww);
    k_cvt<<<(NT * DIM / 8) / 256, 256, 0, stream>>>(x, xbf, NT * DIM);
    {
        dim3 g(FF / 64, DIM / 64, NE);
        k_tcvt<<<g, 256, 0, stream>>>(W1, w1t, DIM, FF);
    }
    {
        dim3 g(DIM / 64, FF / 64, NE);
        k_tcvt<<<g, 256, 0, stream>>>(W2, w2t, FF, DIM);
    }
    k_gemm1<<<G1X, 512, 0, stream>>>(xbf, w1t, rows, offs, counts, tblE, tblM, nmb, Hbuf);
    k_gemm2<<<G2X, 512, 0, stream>>>(Hbuf, w2t, rows, roww, offs, counts, tblE, tblM, nmb, out);
}

// Round 5
// 925.521 us; speedup vs baseline: 1.0830x; 1.0830x over previous
//
#include <hip/hip_runtime.h>
#include <hip/hip_bf16.h>

using u16 = unsigned short;
using u32 = unsigned int;

typedef __bf16 bf16x8 __attribute__((ext_vector_type(8)));
typedef float f32x4 __attribute__((ext_vector_type(4)));
typedef float f32x4v __attribute__((ext_vector_type(4)));
typedef unsigned short u16x8 __attribute__((ext_vector_type(8)));

constexpr int NT  = 8192;   // B*T tokens
constexpr int DIM = 1024;
constexpr int FF  = 4096;
constexpr int NE  = 8;      // experts

constexpr int BM = 128, BN = 128, BK = 64;
constexpr int MAXMB = 136;              // max m-blocks: NT*2/BM + NE
constexpr int G1X = MAXMB * (FF / BN);  // 136*32 = 4352  (%8==0)
constexpr int G2X = MAXMB * (DIM / BN); // 136*8  = 1088  (%8==0)

__device__ inline u16 f2bf(float f) {
    u32 u = __float_as_uint(f);
    u32 r = (u + 0x7fffu + ((u >> 16) & 1u)) >> 16;
    return (u16)r;
}

// direct global->LDS, 16B per lane, wave-uniform LDS base + lane*16
__device__ inline void gload16(const void* g, void* l) {
    __builtin_amdgcn_global_load_lds(
        (const __attribute__((address_space(1))) void*)g,
        (__attribute__((address_space(3))) void*)l, 16, 0, 0);
}

// ---------------- router: logits -> top2 -> softmax weights ----------------
__global__ __launch_bounds__(256) void k_router(const float* __restrict__ x,
                                                const float* __restrict__ Wr,
                                                int* __restrict__ topi,
                                                float* __restrict__ topw,
                                                int* __restrict__ counts) {
    int w = threadIdx.x >> 6, lane = threadIdx.x & 63;
    int t = blockIdx.x * 4 + w;
    const float* xt = x + (size_t)t * DIM;
    float acc[NE];
#pragma unroll
    for (int e = 0; e < NE; e++) acc[e] = 0.f;
    for (int i = 0; i < DIM / 64; i++) {
        int d = i * 64 + lane;
        float xv = xt[d];
#pragma unroll
        for (int e = 0; e < NE; e++) acc[e] += xv * Wr[e * DIM + d];
    }
#pragma unroll
    for (int e = 0; e < NE; e++) {
#pragma unroll
        for (int off = 32; off >= 1; off >>= 1) acc[e] += __shfl_xor(acc[e], off, 64);
    }
    if (lane == 0) {
        int b0 = 0; float v0 = acc[0];
        for (int e = 1; e < NE; e++) if (acc[e] > v0) { v0 = acc[e]; b0 = e; }
        int b1 = -1; float v1 = -INFINITY;
        for (int e = 0; e < NE; e++) if (e != b0 && acc[e] > v1) { v1 = acc[e]; b1 = e; }
        float e1 = __expf(v1 - v0);
        float w0 = 1.f / (1.f + e1);
        topi[t * 2] = b0; topi[t * 2 + 1] = b1;
        topw[t * 2] = w0; topw[t * 2 + 1] = 1.f - w0;
        atomicAdd(&counts[b0], 1);
        atomicAdd(&counts[b1], 1);
    }
}

// prefix + m-block table (expert id, local m0) for grid compaction
__global__ void k_prefix(const int* __restrict__ counts, int* __restrict__ offs,
                         int* __restrict__ cursor, int* __restrict__ tblE,
                         int* __restrict__ tblM, int* __restrict__ nmb) {
    if (threadIdx.x == 0) {
        int s = 0, idx = 0;
        for (int e = 0; e < NE; e++) {
            offs[e] = s; cursor[e] = s;
            int nb = (counts[e] + BM - 1) / BM;
            for (int b = 0; b < nb; b++) { tblE[idx] = e; tblM[idx] = b * BM; idx++; }
            s += counts[e];
        }
        *nmb = idx;
    }
}

__global__ __launch_bounds__(256) void k_build(const int* __restrict__ topi,
                                               const float* __restrict__ topw,
                                               int* __restrict__ cursor,
                                               int* __restrict__ rows,
                                               float* __restrict__ roww) {
    int t = blockIdx.x * 256 + threadIdx.x;
    if (t >= NT) return;
#pragma unroll
    for (int s = 0; s < 2; s++) {
        int e = topi[t * 2 + s];
        int p = atomicAdd(&cursor[e], 1);
        rows[p] = t * 2 + s;
        roww[p] = topw[t * 2 + s];
    }
}

// ---------------- fp32 -> bf16 convert (x) ----------------
__global__ __launch_bounds__(256) void k_cvt(const float* __restrict__ in,
                                             u16* __restrict__ out, int n) {
    int i = blockIdx.x * 256 + threadIdx.x;
    int base = i * 8;
    if (base >= n) return;
    const f32x4v* in4 = reinterpret_cast<const f32x4v*>(in + base);
    f32x4v a = in4[0], b = in4[1];
    u16x8 o;
#pragma unroll
    for (int j = 0; j < 4; j++) { o[j] = f2bf(a[j]); o[j + 4] = f2bf(b[j]); }
    *reinterpret_cast<u16x8*>(out + base) = o;
}

// ---------------- transpose + convert: in [R][C] fp32 -> out [C][R] bf16 ----------------
__global__ __launch_bounds__(256) void k_tcvt(const float* __restrict__ in,
                                              u16* __restrict__ out, int R, int C) {
    __shared__ float tile[64][65];
    int e = blockIdx.z;
    const float* pin = in + (size_t)e * R * C;
    u16* pout = out + (size_t)e * R * C;
    int c0 = blockIdx.x * 64, r0 = blockIdx.y * 64;
    int t = threadIdx.x;
    int lc = (t & 15) * 4, lr = t >> 4;
#pragma unroll
    for (int i = 0; i < 4; i++) {
        int r = lr + i * 16;
        f32x4v v = *reinterpret_cast<const f32x4v*>(&pin[(size_t)(r0 + r) * C + c0 + lc]);
        tile[r][lc] = v[0]; tile[r][lc + 1] = v[1];
        tile[r][lc + 2] = v[2]; tile[r][lc + 3] = v[3];
    }
    __syncthreads();
    int oc = (t & 7) * 8;
    int orow = t >> 3;
#pragma unroll
    for (int i = 0; i < 2; i++) {
        int cc = orow + i * 32;
        u16x8 o;
#pragma unroll
        for (int j = 0; j < 8; j++) o[j] = f2bf(tile[oc + j][cc]);
        *reinterpret_cast<u16x8*>(&pout[(size_t)(c0 + cc) * R + r0 + oc]) = o;
    }
}

// ======== shared 128x128x64 2-phase recipe machinery ========
// LDS tile swizzle: chunk c: row=c>>3, col-chunk g=(c&7)^(row&7); staged via
// pre-swizzled global source + linear LDS dest (both-sides rule).
// frag read: elem = row*BK + ((kk*4+(lane>>4)) ^ (row&7))*8

#define STAGE(buf, kt) do { \
    _Pragma("unroll") for (int i_ = 0; i_ < 4; i_++) \
        gload16(aSrc[i_] + (kt) * BK, &Als[buf][i_ * 2048 + ldsOff]); \
    _Pragma("unroll") for (int i_ = 0; i_ < 4; i_++) \
        gload16(bSrc[i_] + (kt) * BK, &Bls[buf][i_ * 2048 + ldsOff]); \
} while (0)

#define COMPUTE(cur) do { \
    bf16x8 af[2][4], bfr[2][4]; \
    const u16* Ab = &Als[cur][0]; const u16* Bb = &Bls[cur][0]; \
    _Pragma("unroll") for (int kk = 0; kk < 2; kk++) { \
        _Pragma("unroll") for (int mi = 0; mi < 4; mi++) { \
            int row = wr * 64 + mi * 16 + (lane & 15); \
            int s = (kk * 4 + (lane >> 4)) ^ (row & 7); \
            af[kk][mi] = *reinterpret_cast<const bf16x8*>(&Ab[row * BK + s * 8]); } \
        _Pragma("unroll") for (int nj = 0; nj < 4; nj++) { \
            int row = wc * 64 + nj * 16 + (lane & 15); \
            int s = (kk * 4 + (lane >> 4)) ^ (row & 7); \
            bfr[kk][nj] = *reinterpret_cast<const bf16x8*>(&Bb[row * BK + s * 8]); } } \
    __builtin_amdgcn_s_setprio(1); \
    _Pragma("unroll") for (int kk = 0; kk < 2; kk++) \
    _Pragma("unroll") for (int mi = 0; mi < 4; mi++) \
    _Pragma("unroll") for (int nj = 0; nj < 4; nj++) \
        acc[mi][nj] = __builtin_amdgcn_mfma_f32_16x16x32_bf16(af[kk][mi], bfr[kk][nj], acc[mi][nj], 0, 0, 0); \
    __builtin_amdgcn_s_setprio(0); \
} while (0)

// ---------------- GEMM1: H = gelu(x @ W1[e]); minimal 2-phase dbuf ----------------
__global__ __launch_bounds__(256, 2) void k_gemm1(const u16* __restrict__ xbf,
                                                  const u16* __restrict__ w1t, // [E][FF][DIM]
                                                  const int* __restrict__ rows,
                                                  const int* __restrict__ offs,
                                                  const int* __restrict__ counts,
                                                  const int* __restrict__ tblE,
                                                  const int* __restrict__ tblM,
                                                  const int* __restrict__ nmb,
                                                  u16* __restrict__ H) {
    int nwg = G1X;
    int l = ((int)blockIdx.x & 7) * (nwg >> 3) + ((int)blockIdx.x >> 3);
    int xm = l >> 5, yn = l & 31;   // yn inner: A-panel L2-hot per XCD
    if (xm >= *nmb) return;
    int e = tblE[xm], m0 = tblM[xm];
    int cnt = counts[e], off = offs[e];
    int n0 = yn * BN;

    __shared__ __align__(16) u16 Als[2][BM * BK];
    __shared__ __align__(16) u16 Bls[2][BN * BK];

    int tid = threadIdx.x;
    int lane = tid & 63, wid = tid >> 6;
    int wr = wid >> 1, wc = wid & 1;

    f32x4 acc[4][4];
#pragma unroll
    for (int i = 0; i < 4; i++)
#pragma unroll
        for (int j = 0; j < 4; j++) acc[i][j] = (f32x4)(0.f);

    const u16* aSrc[4];
    const u16* bSrc[4];
#pragma unroll
    for (int i = 0; i < 4; i++) {
        int row = i * 32 + (tid >> 3);
        int g = (tid & 7) ^ (row & 7);
        int lrow = m0 + row;
        int tok = (lrow < cnt) ? (rows[off + lrow] >> 1) : 0;
        aSrc[i] = xbf + (size_t)tok * DIM + g * 8;
        bSrc[i] = w1t + (size_t)e * FF * DIM + (size_t)(n0 + row) * DIM + g * 8;
    }
    int ldsOff = wid * 512;   // elems; + i*2048 per chunk

    constexpr int NKT = DIM / BK;  // 16
    STAGE(0, 0);
    __syncthreads();
#pragma unroll 1
    for (int t = 0; t + 2 < NKT; t += 2) {
        STAGE(1, t + 1);
        COMPUTE(0);
        __syncthreads();
        STAGE(0, t + 2);
        COMPUTE(1);
        __syncthreads();
    }
    STAGE(1, NKT - 1);
    COMPUTE(0);
    __syncthreads();
    COMPUTE(1);

    // epilogue: exact GELU -> bf16 H
#pragma unroll
    for (int mi = 0; mi < 4; mi++) {
#pragma unroll
        for (int r = 0; r < 4; r++) {
            int lrow = m0 + wr * 64 + mi * 16 + ((lane >> 4) << 2) + r;
            if (lrow >= cnt) continue;
            u16* hp = H + (size_t)(off + lrow) * FF + n0 + wc * 64;
#pragma unroll
            for (int nj = 0; nj < 4; nj++) {
                float v = acc[mi][nj][r];
                v = 0.5f * v * (1.f + erff(v * 0.70710678118f));
                hp[nj * 16 + (lane & 15)] = f2bf(v);
            }
        }
    }
}

// ---------------- GEMM2: out[token] += w * (H[row] @ W2[e]) ----------------
__global__ __launch_bounds__(256, 2) void k_gemm2(const u16* __restrict__ H,
                                                  const u16* __restrict__ w2t, // [E][DIM][FF]
                                                  const int* __restrict__ rows,
                                                  const float* __restrict__ roww,
                                                  const int* __restrict__ offs,
                                                  const int* __restrict__ counts,
                                                  const int* __restrict__ tblE,
                                                  const int* __restrict__ tblM,
                                                  const int* __restrict__ nmb,
                                                  float* __restrict__ out) {
    int nwg = G2X;
    int l = ((int)blockIdx.x & 7) * (nwg >> 3) + ((int)blockIdx.x >> 3);
    int xm = l >> 3, yn = l & 7;    // yn inner: H-panel L2-hot per XCD
    if (xm >= *nmb) return;
    int e = tblE[xm], m0 = tblM[xm];
    int cnt = counts[e], off = offs[e];
    int n0 = yn * BN;

    __shared__ __align__(16) u16 Als[2][BM * BK];
    __shared__ __align__(16) u16 Bls[2][BN * BK];

    int tid = threadIdx.x;
    int lane = tid & 63, wid = tid >> 6;
    int wr = wid >> 1, wc = wid & 1;

    f32x4 acc[4][4];
#pragma unroll
    for (int i = 0; i < 4; i++)
#pragma unroll
        for (int j = 0; j < 4; j++) acc[i][j] = (f32x4)(0.f);

    const u16* aSrc[4];
    const u16* bSrc[4];
#pragma unroll
    for (int i = 0; i < 4; i++) {
        int row = i * 32 + (tid >> 3);
        int g = (tid & 7) ^ (row & 7);
        int lrow = m0 + row;
        int grow = off + ((lrow < cnt) ? lrow : (cnt - 1));
        aSrc[i] = H + (size_t)grow * FF + g * 8;
        bSrc[i] = w2t + (size_t)e * DIM * FF + (size_t)(n0 + row) * FF + g * 8;
    }
    int ldsOff = wid * 512;

    constexpr int NKT = FF / BK;  // 64
    STAGE(0, 0);
    __syncthreads();
#pragma unroll 1
    for (int t = 0; t + 2 < NKT; t += 2) {
        STAGE(1, t + 1);
        COMPUTE(0);
        __syncthreads();
        STAGE(0, t + 2);
        COMPUTE(1);
        __syncthreads();
    }
    STAGE(1, NKT - 1);
    COMPUTE(0);
    __syncthreads();
    COMPUTE(1);

#pragma unroll
    for (int mi = 0; mi < 4; mi++) {
#pragma unroll
        for (int r = 0; r < 4; r++) {
            int lrow = m0 + wr * 64 + mi * 16 + ((lane >> 4) << 2) + r;
            if (lrow >= cnt) continue;
            int rv = rows[off + lrow];
            float wgt = roww[off + lrow];
            float* op = out + (size_t)(rv >> 1) * DIM + n0 + wc * 64;
#pragma unroll
            for (int nj = 0; nj < 4; nj++)
                atomicAdd(&op[nj * 16 + (lane & 15)], wgt * acc[mi][nj][r]);
        }
    }
}

extern "C" void kernel_launch(void* const* d_in, const int* in_sizes, int n_in,
                              void* d_out, int out_size, void* d_ws, size_t ws_size,
                              hipStream_t stream) {
    const float* x  = (const float*)d_in[0];
    const float* Wr = (const float*)d_in[1];
    const float* W1 = (const float*)d_in[2];
    const float* W2 = (const float*)d_in[3];
    float* out = (float*)d_out;

    char* w = (char*)d_ws;
    size_t o = 0;
    auto carve = [&](size_t bytes) -> void* {
        void* p = w + o;
        o = (o + bytes + 255) & ~(size_t)255;
        return p;
    };
    int*   counts = (int*)carve(NE * 4);
    int*   offs   = (int*)carve(NE * 4);
    int*   cursor = (int*)carve(NE * 4);
    int*   tblE   = (int*)carve(MAXMB * 4);
    int*   tblM   = (int*)carve(MAXMB * 4);
    int*   nmb    = (int*)carve(4);
    int*   topi   = (int*)carve((size_t)NT * 2 * 4);
    float* topw   = (float*)carve((size_t)NT * 2 * 4);
    int*   rows   = (int*)carve((size_t)NT * 2 * 4);
    float* roww   = (float*)carve((size_t)NT * 2 * 4);
    u16*   xbf    = (u16*)carve((size_t)NT * DIM * 2);
    u16*   w1t    = (u16*)carve((size_t)NE * DIM * FF * 2);
    u16*   w2t    = (u16*)carve((size_t)NE * DIM * FF * 2);
    u16*   Hbuf   = (u16*)carve((size_t)NT * 2 * FF * 2);
    (void)ws_size; (void)in_sizes; (void)n_in; (void)out_size;

    hipMemsetAsync(counts, 0, NE * 4, stream);
    hipMemsetAsync(d_out, 0, (size_t)NT * DIM * 4, stream);

    k_router<<<NT / 4, 256, 0, stream>>>(x, Wr, topi, topw, counts);
    k_prefix<<<1, 64, 0, stream>>>(counts, offs, cursor, tblE, tblM, nmb);
    k_build<<<NT / 256, 256, 0, stream>>>(topi, topw, cursor, rows, roww);
    k_cvt<<<(NT * DIM / 8) / 256, 256, 0, stream>>>(x, xbf, NT * DIM);
    {
        dim3 g(FF / 64, DIM / 64, NE);
        k_tcvt<<<g, 256, 0, stream>>>(W1, w1t, DIM, FF);
    }
    {
        dim3 g(DIM / 64, FF / 64, NE);
        k_tcvt<<<g, 256, 0, stream>>>(W2, w2t, FF, DIM);
    }
    k_gemm1<<<G1X, 256, 0, stream>>>(xbf, w1t, rows, offs, counts, tblE, tblM, nmb, Hbuf);
    k_gemm2<<<G2X, 256, 0, stream>>>(Hbuf, w2t, rows, roww, offs, counts, tblE, tblM, nmb, out);
}

// Round 6
// 895.746 us; speedup vs baseline: 1.1190x; 1.0332x over previous
//
#include <hip/hip_runtime.h>
#include <hip/hip_bf16.h>

using u16 = unsigned short;
using u32 = unsigned int;

typedef __bf16 bf16x8 __attribute__((ext_vector_type(8)));
typedef float f32x4 __attribute__((ext_vector_type(4)));
typedef float f32x4v __attribute__((ext_vector_type(4)));
typedef unsigned short u16x8 __attribute__((ext_vector_type(8)));

constexpr int NT  = 8192;   // B*T tokens
constexpr int DIM = 1024;
constexpr int FF  = 4096;
constexpr int NE  = 8;      // experts

// gemm1: 256x256x64, 512 thr. gemm2: 128x128x64, 256 thr.
constexpr int BM1 = 256, BN1 = 256;
constexpr int BM2g = 128, BN2g = 128;
constexpr int BK = 64;
constexpr int MAXMB1 = NT * 2 / BM1 + NE;   // 72
constexpr int MAXMB2 = NT * 2 / BM2g + NE;  // 136
constexpr int G1X = MAXMB1 * (FF / BN1);    // 72*16 = 1152 (%8==0)
constexpr int G2X = MAXMB2 * (DIM / BN2g);  // 136*8 = 1088 (%8==0)

__device__ inline u16 f2bf(float f) {
    u32 u = __float_as_uint(f);
    u32 r = (u + 0x7fffu + ((u >> 16) & 1u)) >> 16;
    return (u16)r;
}

// direct global->LDS, 16B per lane, wave-uniform LDS base + lane*16
__device__ inline void gload16(const void* g, void* l) {
    __builtin_amdgcn_global_load_lds(
        (const __attribute__((address_space(1))) void*)g,
        (__attribute__((address_space(3))) void*)l, 16, 0, 0);
}

// ---------------- router: logits -> top2 -> softmax weights ----------------
__global__ __launch_bounds__(256) void k_router(const float* __restrict__ x,
                                                const float* __restrict__ Wr,
                                                int* __restrict__ topi,
                                                float* __restrict__ topw,
                                                int* __restrict__ counts) {
    int w = threadIdx.x >> 6, lane = threadIdx.x & 63;
    int t = blockIdx.x * 4 + w;
    const float* xt = x + (size_t)t * DIM;
    float acc[NE];
#pragma unroll
    for (int e = 0; e < NE; e++) acc[e] = 0.f;
    for (int i = 0; i < DIM / 64; i++) {
        int d = i * 64 + lane;
        float xv = xt[d];
#pragma unroll
        for (int e = 0; e < NE; e++) acc[e] += xv * Wr[e * DIM + d];
    }
#pragma unroll
    for (int e = 0; e < NE; e++) {
#pragma unroll
        for (int off = 32; off >= 1; off >>= 1) acc[e] += __shfl_xor(acc[e], off, 64);
    }
    if (lane == 0) {
        int b0 = 0; float v0 = acc[0];
        for (int e = 1; e < NE; e++) if (acc[e] > v0) { v0 = acc[e]; b0 = e; }
        int b1 = -1; float v1 = -INFINITY;
        for (int e = 0; e < NE; e++) if (e != b0 && acc[e] > v1) { v1 = acc[e]; b1 = e; }
        float e1 = __expf(v1 - v0);
        float w0 = 1.f / (1.f + e1);
        topi[t * 2] = b0; topi[t * 2 + 1] = b1;
        topw[t * 2] = w0; topw[t * 2 + 1] = 1.f - w0;
        atomicAdd(&counts[b0], 1);
        atomicAdd(&counts[b1], 1);
    }
}

// prefix + m-block tables at both granularities (256 for gemm1, 128 for gemm2)
__global__ void k_prefix(const int* __restrict__ counts, int* __restrict__ offs,
                         int* __restrict__ cursor,
                         int* __restrict__ tblE1, int* __restrict__ tblM1, int* __restrict__ nmb1,
                         int* __restrict__ tblE2, int* __restrict__ tblM2, int* __restrict__ nmb2) {
    if (threadIdx.x == 0) {
        int s = 0, i1 = 0, i2 = 0;
        for (int e = 0; e < NE; e++) {
            offs[e] = s; cursor[e] = s;
            int nb1 = (counts[e] + BM1 - 1) / BM1;
            for (int b = 0; b < nb1; b++) { tblE1[i1] = e; tblM1[i1] = b * BM1; i1++; }
            int nb2 = (counts[e] + BM2g - 1) / BM2g;
            for (int b = 0; b < nb2; b++) { tblE2[i2] = e; tblM2[i2] = b * BM2g; i2++; }
            s += counts[e];
        }
        *nmb1 = i1; *nmb2 = i2;
    }
}

__global__ __launch_bounds__(256) void k_build(const int* __restrict__ topi,
                                               const float* __restrict__ topw,
                                               int* __restrict__ cursor,
                                               int* __restrict__ rows,
                                               float* __restrict__ roww) {
    int t = blockIdx.x * 256 + threadIdx.x;
    if (t >= NT) return;
#pragma unroll
    for (int s = 0; s < 2; s++) {
        int e = topi[t * 2 + s];
        int p = atomicAdd(&cursor[e], 1);
        rows[p] = t * 2 + s;
        roww[p] = topw[t * 2 + s];
    }
}

// ---------------- fp32 -> bf16 convert (x) ----------------
__global__ __launch_bounds__(256) void k_cvt(const float* __restrict__ in,
                                             u16* __restrict__ out, int n) {
    int i = blockIdx.x * 256 + threadIdx.x;
    int base = i * 8;
    if (base >= n) return;
    const f32x4v* in4 = reinterpret_cast<const f32x4v*>(in + base);
    f32x4v a = in4[0], b = in4[1];
    u16x8 o;
#pragma unroll
    for (int j = 0; j < 4; j++) { o[j] = f2bf(a[j]); o[j + 4] = f2bf(b[j]); }
    *reinterpret_cast<u16x8*>(out + base) = o;
}

// ---------------- transpose + convert: in [R][C] fp32 -> out [C][R] bf16 ----------------
__global__ __launch_bounds__(256) void k_tcvt(const float* __restrict__ in,
                                              u16* __restrict__ out, int R, int C) {
    __shared__ float tile[64][65];
    int e = blockIdx.z;
    const float* pin = in + (size_t)e * R * C;
    u16* pout = out + (size_t)e * R * C;
    int c0 = blockIdx.x * 64, r0 = blockIdx.y * 64;
    int t = threadIdx.x;
    int lc = (t & 15) * 4, lr = t >> 4;
#pragma unroll
    for (int i = 0; i < 4; i++) {
        int r = lr + i * 16;
        f32x4v v = *reinterpret_cast<const f32x4v*>(&pin[(size_t)(r0 + r) * C + c0 + lc]);
        tile[r][lc] = v[0]; tile[r][lc + 1] = v[1];
        tile[r][lc + 2] = v[2]; tile[r][lc + 3] = v[3];
    }
    __syncthreads();
    int oc = (t & 7) * 8;
    int orow = t >> 3;
#pragma unroll
    for (int i = 0; i < 2; i++) {
        int cc = orow + i * 32;
        u16x8 o;
#pragma unroll
        for (int j = 0; j < 8; j++) o[j] = f2bf(tile[oc + j][cc]);
        *reinterpret_cast<u16x8*>(&pout[(size_t)(c0 + cc) * R + r0 + oc]) = o;
    }
}

// ---------------- GEMM1: H = gelu(x @ W1[e]); 256x256x64, 2-barrier/tile ----------------
// LDS swizzle (both-sides): stage chunk c: row=c>>3, src col-chunk g=(c&7)^(row&7),
// linear LDS dest; frag read slot s=(ks*4+(lane>>4))^(row&7).
__global__ __launch_bounds__(512, 2) void k_gemm1(const u16* __restrict__ xbf,
                                                  const u16* __restrict__ w1t, // [E][FF][DIM]
                                                  const int* __restrict__ rows,
                                                  const int* __restrict__ offs,
                                                  const int* __restrict__ counts,
                                                  const int* __restrict__ tblE,
                                                  const int* __restrict__ tblM,
                                                  const int* __restrict__ nmb,
                                                  u16* __restrict__ H) {
    __shared__ __align__(16) u16 As[2][BM1 * BK];
    __shared__ __align__(16) u16 Bs[2][BN1 * BK];

    int l = ((int)blockIdx.x & 7) * (G1X >> 3) + ((int)blockIdx.x >> 3);
    int yn = l / MAXMB1, xm = l % MAXMB1;   // xm inner: B-panel L2-hot per XCD
    if (xm >= *nmb) return;
    int e = tblE[xm], m0 = tblM[xm];
    int cnt = counts[e], off = offs[e];
    int n0 = yn * BN1;

    int tid = threadIdx.x, lane = tid & 63, wid = tid >> 6;
    int wm = wid >> 2, wn = wid & 3;        // 2M x 4N waves; per-wave 128x64 out

    f32x4 acc[8][4];
#pragma unroll
    for (int i = 0; i < 8; i++)
#pragma unroll
        for (int j = 0; j < 4; j++) acc[i][j] = (f32x4)(0.f);

    const u16* aS[4]; const u16* bS[4];
#pragma unroll
    for (int j = 0; j < 4; j++) {
        int c = j * 512 + tid;
        int row = c >> 3, g = (c & 7) ^ (row & 7);
        int lrow = m0 + row;
        int tok = (lrow < cnt) ? (rows[off + lrow] >> 1) : 0;
        aS[j] = xbf + (size_t)tok * DIM + g * 8;
        bS[j] = w1t + (size_t)e * FF * DIM + (size_t)(n0 + row) * DIM + g * 8;
    }

#define STG1(buf, kt) do { \
    _Pragma("unroll") for (int j_ = 0; j_ < 4; j_++) \
        gload16(aS[j_] + (kt) * BK, &As[buf][j_ * 4096 + wid * 512]); \
    _Pragma("unroll") for (int j_ = 0; j_ < 4; j_++) \
        gload16(bS[j_] + (kt) * BK, &Bs[buf][j_ * 4096 + wid * 512]); \
} while (0)

    constexpr int NKT = DIM / BK;  // 16
    STG1(0, 0);
    STG1(1, 1);
    asm volatile("s_waitcnt vmcnt(8)" ::: "memory");
    __builtin_amdgcn_s_barrier();

#pragma unroll 1
    for (int t = 0; t < NKT; ++t) {
        int cur = t & 1;
        // ---- compute tile t: 4 clusters of 16 MFMA, no intra-tile barriers ----
#pragma unroll
        for (int ks = 0; ks < 2; ks++) {
            bf16x8 bfr[4];
#pragma unroll
            for (int nj = 0; nj < 4; nj++) {
                int row = wn * 64 + nj * 16 + (lane & 15);
                int s = (ks * 4 + (lane >> 4)) ^ (row & 7);
                bfr[nj] = *reinterpret_cast<const bf16x8*>(&Bs[cur][row * 64 + s * 8]);
            }
#pragma unroll
            for (int q = 0; q < 2; q++) {
                bf16x8 af[4];
#pragma unroll
                for (int mi = 0; mi < 4; mi++) {
                    int row = wm * 128 + q * 64 + mi * 16 + (lane & 15);
                    int s = (ks * 4 + (lane >> 4)) ^ (row & 7);
                    af[mi] = *reinterpret_cast<const bf16x8*>(&As[cur][row * 64 + s * 8]);
                }
                __builtin_amdgcn_s_setprio(1);
#pragma unroll
                for (int mi = 0; mi < 4; mi++)
#pragma unroll
                    for (int nj = 0; nj < 4; nj++)
                        acc[q * 4 + mi][nj] = __builtin_amdgcn_mfma_f32_16x16x32_bf16(
                            af[mi], bfr[nj], acc[q * 4 + mi][nj], 0, 0, 0);
                __builtin_amdgcn_s_setprio(0);
            }
        }
        // ---- tile boundary: certify reads done, stage t+2, drain t+1 (counted) ----
        if (t + 2 < NKT) {
            asm volatile("s_waitcnt lgkmcnt(0)" ::: "memory");
            __builtin_amdgcn_s_barrier();
            STG1(cur, t + 2);
            asm volatile("s_waitcnt vmcnt(8)" ::: "memory");
            __builtin_amdgcn_s_barrier();
        } else if (t + 1 < NKT) {
            asm volatile("s_waitcnt lgkmcnt(0)" ::: "memory");
            __builtin_amdgcn_s_barrier();
            asm volatile("s_waitcnt vmcnt(0)" ::: "memory");
            __builtin_amdgcn_s_barrier();
        }
    }
#undef STG1

    // epilogue: exact GELU -> bf16 H
#pragma unroll
    for (int a8 = 0; a8 < 8; a8++) {
#pragma unroll
        for (int r = 0; r < 4; r++) {
            int lrow = m0 + wm * 128 + (a8 >> 2) * 64 + (a8 & 3) * 16 + ((lane >> 4) << 2) + r;
            if (lrow >= cnt) continue;
            u16* hp = H + (size_t)(off + lrow) * FF + n0 + wn * 64;
#pragma unroll
            for (int nj = 0; nj < 4; nj++) {
                float v = acc[a8][nj][r];
                v = 0.5f * v * (1.f + erff(v * 0.70710678118f));
                hp[nj * 16 + (lane & 15)] = f2bf(v);
            }
        }
    }
}

// ---------------- GEMM2: out[token] += w * (H[row] @ W2[e]); 128x128x64 ----------------
__global__ __launch_bounds__(256, 2) void k_gemm2(const u16* __restrict__ H,
                                                  const u16* __restrict__ w2t, // [E][DIM][FF]
                                                  const int* __restrict__ rows,
                                                  const float* __restrict__ roww,
                                                  const int* __restrict__ offs,
                                                  const int* __restrict__ counts,
                                                  const int* __restrict__ tblE,
                                                  const int* __restrict__ tblM,
                                                  const int* __restrict__ nmb,
                                                  float* __restrict__ out) {
    __shared__ __align__(16) u16 As[2][BM2g * BK];
    __shared__ __align__(16) u16 Bs[2][BN2g * BK];

    int l = ((int)blockIdx.x & 7) * (G2X >> 3) + ((int)blockIdx.x >> 3);
    int xm = l >> 3, yn = l & 7;            // yn inner: H-panel L2-hot per XCD
    if (xm >= *nmb) return;
    int e = tblE[xm], m0 = tblM[xm];
    int cnt = counts[e], off = offs[e];
    int n0 = yn * BN2g;

    int tid = threadIdx.x, lane = tid & 63, wid = tid >> 6;
    int wr = wid >> 1, wc = wid & 1;        // 2M x 2N waves; per-wave 64x64 out

    f32x4 acc[4][4];
#pragma unroll
    for (int i = 0; i < 4; i++)
#pragma unroll
        for (int j = 0; j < 4; j++) acc[i][j] = (f32x4)(0.f);

    const u16* aS[4]; const u16* bS[4];
#pragma unroll
    for (int j = 0; j < 4; j++) {
        int c = j * 256 + tid;
        int row = c >> 3, g = (c & 7) ^ (row & 7);
        int lrow = m0 + row;
        int grow = off + ((lrow < cnt) ? lrow : (cnt - 1));
        aS[j] = H + (size_t)grow * FF + g * 8;
        bS[j] = w2t + (size_t)e * DIM * FF + (size_t)(n0 + row) * FF + g * 8;
    }

#define STG2(buf, kt) do { \
    _Pragma("unroll") for (int j_ = 0; j_ < 4; j_++) \
        gload16(aS[j_] + (kt) * BK, &As[buf][j_ * 2048 + wid * 512]); \
    _Pragma("unroll") for (int j_ = 0; j_ < 4; j_++) \
        gload16(bS[j_] + (kt) * BK, &Bs[buf][j_ * 2048 + wid * 512]); \
} while (0)

    constexpr int NKT = FF / BK;  // 64
    STG2(0, 0);
    STG2(1, 1);
    asm volatile("s_waitcnt vmcnt(8)" ::: "memory");
    __builtin_amdgcn_s_barrier();

#pragma unroll 1
    for (int t = 0; t < NKT; ++t) {
        int cur = t & 1;
#pragma unroll
        for (int ks = 0; ks < 2; ks++) {
            bf16x8 bfr[4], af[4];
#pragma unroll
            for (int nj = 0; nj < 4; nj++) {
                int row = wc * 64 + nj * 16 + (lane & 15);
                int s = (ks * 4 + (lane >> 4)) ^ (row & 7);
                bfr[nj] = *reinterpret_cast<const bf16x8*>(&Bs[cur][row * 64 + s * 8]);
            }
#pragma unroll
            for (int mi = 0; mi < 4; mi++) {
                int row = wr * 64 + mi * 16 + (lane & 15);
                int s = (ks * 4 + (lane >> 4)) ^ (row & 7);
                af[mi] = *reinterpret_cast<const bf16x8*>(&As[cur][row * 64 + s * 8]);
            }
            __builtin_amdgcn_s_setprio(1);
#pragma unroll
            for (int mi = 0; mi < 4; mi++)
#pragma unroll
                for (int nj = 0; nj < 4; nj++)
                    acc[mi][nj] = __builtin_amdgcn_mfma_f32_16x16x32_bf16(
                        af[mi], bfr[nj], acc[mi][nj], 0, 0, 0);
            __builtin_amdgcn_s_setprio(0);
        }
        if (t + 2 < NKT) {
            asm volatile("s_waitcnt lgkmcnt(0)" ::: "memory");
            __builtin_amdgcn_s_barrier();
            STG2(cur, t + 2);
            asm volatile("s_waitcnt vmcnt(8)" ::: "memory");
            __builtin_amdgcn_s_barrier();
        } else if (t + 1 < NKT) {
            asm volatile("s_waitcnt lgkmcnt(0)" ::: "memory");
            __builtin_amdgcn_s_barrier();
            asm volatile("s_waitcnt vmcnt(0)" ::: "memory");
            __builtin_amdgcn_s_barrier();
        }
    }
#undef STG2

#pragma unroll
    for (int mi = 0; mi < 4; mi++) {
#pragma unroll
        for (int r = 0; r < 4; r++) {
            int lrow = m0 + wr * 64 + mi * 16 + ((lane >> 4) << 2) + r;
            if (lrow >= cnt) continue;
            int rv = rows[off + lrow];
            float wgt = roww[off + lrow];
            float* op = out + (size_t)(rv >> 1) * DIM + n0 + wc * 64;
#pragma unroll
            for (int nj = 0; nj < 4; nj++)
                atomicAdd(&op[nj * 16 + (lane & 15)], wgt * acc[mi][nj][r]);
        }
    }
}

extern "C" void kernel_launch(void* const* d_in, const int* in_sizes, int n_in,
                              void* d_out, int out_size, void* d_ws, size_t ws_size,
                              hipStream_t stream) {
    const float* x  = (const float*)d_in[0];
    const float* Wr = (const float*)d_in[1];
    const float* W1 = (const float*)d_in[2];
    const float* W2 = (const float*)d_in[3];
    float* out = (float*)d_out;

    char* w = (char*)d_ws;
    size_t o = 0;
    auto carve = [&](size_t bytes) -> void* {
        void* p = w + o;
        o = (o + bytes + 255) & ~(size_t)255;
        return p;
    };
    int*   counts = (int*)carve(NE * 4);
    int*   offs   = (int*)carve(NE * 4);
    int*   cursor = (int*)carve(NE * 4);
    int*   tblE1  = (int*)carve(MAXMB1 * 4);
    int*   tblM1  = (int*)carve(MAXMB1 * 4);
    int*   nmb1   = (int*)carve(4);
    int*   tblE2  = (int*)carve(MAXMB2 * 4);
    int*   tblM2  = (int*)carve(MAXMB2 * 4);
    int*   nmb2   = (int*)carve(4);
    int*   topi   = (int*)carve((size_t)NT * 2 * 4);
    float* topw   = (float*)carve((size_t)NT * 2 * 4);
    int*   rows   = (int*)carve((size_t)NT * 2 * 4);
    float* roww   = (float*)carve((size_t)NT * 2 * 4);
    u16*   xbf    = (u16*)carve((size_t)NT * DIM * 2);
    u16*   w1t    = (u16*)carve((size_t)NE * DIM * FF * 2);
    u16*   w2t    = (u16*)carve((size_t)NE * DIM * FF * 2);
    u16*   Hbuf   = (u16*)carve((size_t)NT * 2 * FF * 2);
    (void)ws_size; (void)in_sizes; (void)n_in; (void)out_size;

    hipMemsetAsync(counts, 0, NE * 4, stream);
    hipMemsetAsync(d_out, 0, (size_t)NT * DIM * 4, stream);

    k_router<<<NT / 4, 256, 0, stream>>>(x, Wr, topi, topw, counts);
    k_prefix<<<1, 64, 0, stream>>>(counts, offs, cursor, tblE1, tblM1, nmb1, tblE2, tblM2, nmb2);
    k_build<<<NT / 256, 256, 0, stream>>>(topi, topw, cursor, rows, roww);
    k_cvt<<<(NT * DIM / 8) / 256, 256, 0, stream>>>(x, xbf, NT * DIM);
    {
        dim3 g(FF / 64, DIM / 64, NE);
        k_tcvt<<<g, 256, 0, stream>>>(W1, w1t, DIM, FF);
    }
    {
        dim3 g(DIM / 64, FF / 64, NE);
        k_tcvt<<<g, 256, 0, stream>>>(W2, w2t, FF, DIM);
    }
    k_gemm1<<<G1X, 512, 0, stream>>>(xbf, w1t, rows, offs, counts, tblE1, tblM1, nmb1, Hbuf);
    k_gemm2<<<G2X, 256, 0, stream>>>(Hbuf, w2t, rows, roww, offs, counts, tblE2, tblM2, nmb2, out);
}

// Round 7
// 778.515 us; speedup vs baseline: 1.2875x; 1.1506x over previous
//
#include <hip/hip_runtime.h>
#include <hip/hip_bf16.h>

using u16 = unsigned short;
using u32 = unsigned int;

typedef __bf16 bf16x8 __attribute__((ext_vector_type(8)));
typedef float f32x4 __attribute__((ext_vector_type(4)));
typedef float f32x4v __attribute__((ext_vector_type(4)));
typedef unsigned short u16x8 __attribute__((ext_vector_type(8)));

constexpr int NT  = 8192;   // B*T tokens
constexpr int DIM = 1024;
constexpr int FF  = 4096;
constexpr int NE  = 8;      // experts

constexpr int BM = 128, BN = 128, BK = 64;
constexpr int MAXMB = 136;              // max m-blocks: NT*2/BM + NE
constexpr int G1X = MAXMB * (FF / BN);  // 136*32 = 4352  (%8==0)
constexpr int G2X = MAXMB * (DIM / BN); // 136*8  = 1088  (%8==0)

__device__ inline u16 f2bf(float f) {
    u32 u = __float_as_uint(f);
    u32 r = (u + 0x7fffu + ((u >> 16) & 1u)) >> 16;
    return (u16)r;
}

// direct global->LDS, 16B per lane, wave-uniform LDS base + lane*16
__device__ inline void gload16(const void* g, void* l) {
    __builtin_amdgcn_global_load_lds(
        (const __attribute__((address_space(1))) void*)g,
        (__attribute__((address_space(3))) void*)l, 16, 0, 0);
}

// ---------------- router: logits -> top2 -> softmax weights ----------------
__global__ __launch_bounds__(256) void k_router(const float* __restrict__ x,
                                                const float* __restrict__ Wr,
                                                int* __restrict__ topi,
                                                float* __restrict__ topw,
                                                int* __restrict__ counts) {
    int w = threadIdx.x >> 6, lane = threadIdx.x & 63;
    int t = blockIdx.x * 4 + w;
    const float* xt = x + (size_t)t * DIM;
    float acc[NE];
#pragma unroll
    for (int e = 0; e < NE; e++) acc[e] = 0.f;
    for (int i = 0; i < DIM / 64; i++) {
        int d = i * 64 + lane;
        float xv = xt[d];
#pragma unroll
        for (int e = 0; e < NE; e++) acc[e] += xv * Wr[e * DIM + d];
    }
#pragma unroll
    for (int e = 0; e < NE; e++) {
#pragma unroll
        for (int off = 32; off >= 1; off >>= 1) acc[e] += __shfl_xor(acc[e], off, 64);
    }
    if (lane == 0) {
        int b0 = 0; float v0 = acc[0];
        for (int e = 1; e < NE; e++) if (acc[e] > v0) { v0 = acc[e]; b0 = e; }
        int b1 = -1; float v1 = -INFINITY;
        for (int e = 0; e < NE; e++) if (e != b0 && acc[e] > v1) { v1 = acc[e]; b1 = e; }
        float e1 = __expf(v1 - v0);
        float w0 = 1.f / (1.f + e1);
        topi[t * 2] = b0; topi[t * 2 + 1] = b1;
        topw[t * 2] = w0; topw[t * 2 + 1] = 1.f - w0;
        atomicAdd(&counts[b0], 1);
        atomicAdd(&counts[b1], 1);
    }
}

// prefix + m-block table (expert id, local m0) for grid compaction
__global__ void k_prefix(const int* __restrict__ counts, int* __restrict__ offs,
                         int* __restrict__ cursor, int* __restrict__ tblE,
                         int* __restrict__ tblM, int* __restrict__ nmb) {
    if (threadIdx.x == 0) {
        int s = 0, idx = 0;
        for (int e = 0; e < NE; e++) {
            offs[e] = s; cursor[e] = s;
            int nb = (counts[e] + BM - 1) / BM;
            for (int b = 0; b < nb; b++) { tblE[idx] = e; tblM[idx] = b * BM; idx++; }
            s += counts[e];
        }
        *nmb = idx;
    }
}

__global__ __launch_bounds__(256) void k_build(const int* __restrict__ topi,
                                               const float* __restrict__ topw,
                                               int* __restrict__ cursor,
                                               int* __restrict__ rows,
                                               float* __restrict__ roww) {
    int t = blockIdx.x * 256 + threadIdx.x;
    if (t >= NT) return;
#pragma unroll
    for (int s = 0; s < 2; s++) {
        int e = topi[t * 2 + s];
        int p = atomicAdd(&cursor[e], 1);
        rows[p] = t * 2 + s;
        roww[p] = topw[t * 2 + s];
    }
}

// ---------------- fp32 -> bf16 convert (x) ----------------
__global__ __launch_bounds__(256) void k_cvt(const float* __restrict__ in,
                                             u16* __restrict__ out, int n) {
    int i = blockIdx.x * 256 + threadIdx.x;
    int base = i * 8;
    if (base >= n) return;
    const f32x4v* in4 = reinterpret_cast<const f32x4v*>(in + base);
    f32x4v a = in4[0], b = in4[1];
    u16x8 o;
#pragma unroll
    for (int j = 0; j < 4; j++) { o[j] = f2bf(a[j]); o[j + 4] = f2bf(b[j]); }
    *reinterpret_cast<u16x8*>(out + base) = o;
}

// ---------------- transpose + convert: in [R][C] fp32 -> out [C][R] bf16 ----------------
__global__ __launch_bounds__(256) void k_tcvt(const float* __restrict__ in,
                                              u16* __restrict__ out, int R, int C) {
    __shared__ float tile[64][65];
    int e = blockIdx.z;
    const float* pin = in + (size_t)e * R * C;
    u16* pout = out + (size_t)e * R * C;
    int c0 = blockIdx.x * 64, r0 = blockIdx.y * 64;
    int t = threadIdx.x;
    int lc = (t & 15) * 4, lr = t >> 4;
#pragma unroll
    for (int i = 0; i < 4; i++) {
        int r = lr + i * 16;
        f32x4v v = *reinterpret_cast<const f32x4v*>(&pin[(size_t)(r0 + r) * C + c0 + lc]);
        tile[r][lc] = v[0]; tile[r][lc + 1] = v[1];
        tile[r][lc + 2] = v[2]; tile[r][lc + 3] = v[3];
    }
    __syncthreads();
    int oc = (t & 7) * 8;
    int orow = t >> 3;
#pragma unroll
    for (int i = 0; i < 2; i++) {
        int cc = orow + i * 32;
        u16x8 o;
#pragma unroll
        for (int j = 0; j < 8; j++) o[j] = f2bf(tile[oc + j][cc]);
        *reinterpret_cast<u16x8*>(&pout[(size_t)(c0 + cc) * R + r0 + oc]) = o;
    }
}

// ======== m97-style single-buffer 128x128x64 GEMM machinery ========
// LDS swizzle (both-sides): stage chunk c: row=c>>3, src col-chunk g=(c&7)^(row&7),
// linear LDS dest; frag read slot s=(kk*4+(lane>>4))^(row&7). Conflict-free (verified 0).
// Hiding comes from 4 blocks/CU (16 waves) cross-block overlap, not explicit pipeline.

#define STAGE(kt) do { \
    _Pragma("unroll") for (int i_ = 0; i_ < 4; i_++) \
        gload16(aSrc[i_] + (kt) * BK, &Als[i_ * 2048 + ldsOff]); \
    _Pragma("unroll") for (int i_ = 0; i_ < 4; i_++) \
        gload16(bSrc[i_] + (kt) * BK, &Bls[i_ * 2048 + ldsOff]); \
} while (0)

#define COMPUTE() do { \
    bf16x8 af[2][4], bfr[2][4]; \
    _Pragma("unroll") for (int kk = 0; kk < 2; kk++) { \
        _Pragma("unroll") for (int mi = 0; mi < 4; mi++) { \
            int row = wr * 64 + mi * 16 + (lane & 15); \
            int s = (kk * 4 + (lane >> 4)) ^ (row & 7); \
            af[kk][mi] = *reinterpret_cast<const bf16x8*>(&Als[row * BK + s * 8]); } \
        _Pragma("unroll") for (int nj = 0; nj < 4; nj++) { \
            int row = wc * 64 + nj * 16 + (lane & 15); \
            int s = (kk * 4 + (lane >> 4)) ^ (row & 7); \
            bfr[kk][nj] = *reinterpret_cast<const bf16x8*>(&Bls[row * BK + s * 8]); } } \
    _Pragma("unroll") for (int kk = 0; kk < 2; kk++) \
    _Pragma("unroll") for (int mi = 0; mi < 4; mi++) \
    _Pragma("unroll") for (int nj = 0; nj < 4; nj++) \
        acc[mi][nj] = __builtin_amdgcn_mfma_f32_16x16x32_bf16(af[kk][mi], bfr[kk][nj], acc[mi][nj], 0, 0, 0); \
} while (0)

// ---------------- GEMM1: H = gelu(x @ W1[e]) ----------------
__global__ __launch_bounds__(256, 4) void k_gemm1(const u16* __restrict__ xbf,
                                                  const u16* __restrict__ w1t, // [E][FF][DIM]
                                                  const int* __restrict__ rows,
                                                  const int* __restrict__ offs,
                                                  const int* __restrict__ counts,
                                                  const int* __restrict__ tblE,
                                                  const int* __restrict__ tblM,
                                                  const int* __restrict__ nmb,
                                                  u16* __restrict__ H) {
    int l = ((int)blockIdx.x & 7) * (G1X >> 3) + ((int)blockIdx.x >> 3);
    int xm = l >> 5, yn = l & 31;   // yn inner: A-panel (tokens) L2-hot per XCD
    if (xm >= *nmb) return;
    int e = tblE[xm], m0 = tblM[xm];
    int cnt = counts[e], off = offs[e];
    int n0 = yn * BN;

    __shared__ __align__(16) u16 Als[BM * BK];   // 16 KB
    __shared__ __align__(16) u16 Bls[BN * BK];   // 16 KB

    int tid = threadIdx.x;
    int lane = tid & 63, wid = tid >> 6;
    int wr = wid >> 1, wc = wid & 1;

    f32x4 acc[4][4];
#pragma unroll
    for (int i = 0; i < 4; i++)
#pragma unroll
        for (int j = 0; j < 4; j++) acc[i][j] = (f32x4)(0.f);

    const u16* aSrc[4];
    const u16* bSrc[4];
#pragma unroll
    for (int i = 0; i < 4; i++) {
        int row = i * 32 + (tid >> 3);
        int g = (tid & 7) ^ (row & 7);
        int lrow = m0 + row;
        int tok = (lrow < cnt) ? (rows[off + lrow] >> 1) : 0;
        aSrc[i] = xbf + (size_t)tok * DIM + g * 8;
        bSrc[i] = w1t + (size_t)e * FF * DIM + (size_t)(n0 + row) * DIM + g * 8;
    }
    int ldsOff = wid * 512;   // elems; + i*2048 per chunk

    constexpr int NKT = DIM / BK;  // 16
#pragma unroll 1
    for (int kt = 0; kt < NKT; ++kt) {
        STAGE(kt);
        __syncthreads();   // drains vmcnt; tile ready
        COMPUTE();
        __syncthreads();   // reads done; safe to restage
    }

    // epilogue: exact GELU -> bf16 H
#pragma unroll
    for (int mi = 0; mi < 4; mi++) {
#pragma unroll
        for (int r = 0; r < 4; r++) {
            int lrow = m0 + wr * 64 + mi * 16 + ((lane >> 4) << 2) + r;
            if (lrow >= cnt) continue;
            u16* hp = H + (size_t)(off + lrow) * FF + n0 + wc * 64;
#pragma unroll
            for (int nj = 0; nj < 4; nj++) {
                float v = acc[mi][nj][r];
                v = 0.5f * v * (1.f + erff(v * 0.70710678118f));
                hp[nj * 16 + (lane & 15)] = f2bf(v);
            }
        }
    }
}

// ---------------- GEMM2: out[token] += w * (H[row] @ W2[e]) ----------------
__global__ __launch_bounds__(256, 4) void k_gemm2(const u16* __restrict__ H,
                                                  const u16* __restrict__ w2t, // [E][DIM][FF]
                                                  const int* __restrict__ rows,
                                                  const float* __restrict__ roww,
                                                  const int* __restrict__ offs,
                                                  const int* __restrict__ counts,
                                                  const int* __restrict__ tblE,
                                                  const int* __restrict__ tblM,
                                                  const int* __restrict__ nmb,
                                                  float* __restrict__ out) {
    int l = ((int)blockIdx.x & 7) * (G2X >> 3) + ((int)blockIdx.x >> 3);
    int xm = l >> 3, yn = l & 7;    // yn inner: H-panel L2-hot per XCD
    if (xm >= *nmb) return;
    int e = tblE[xm], m0 = tblM[xm];
    int cnt = counts[e], off = offs[e];
    int n0 = yn * BN;

    __shared__ __align__(16) u16 Als[BM * BK];
    __shared__ __align__(16) u16 Bls[BN * BK];

    int tid = threadIdx.x;
    int lane = tid & 63, wid = tid >> 6;
    int wr = wid >> 1, wc = wid & 1;

    f32x4 acc[4][4];
#pragma unroll
    for (int i = 0; i < 4; i++)
#pragma unroll
        for (int j = 0; j < 4; j++) acc[i][j] = (f32x4)(0.f);

    const u16* aSrc[4];
    const u16* bSrc[4];
#pragma unroll
    for (int i = 0; i < 4; i++) {
        int row = i * 32 + (tid >> 3);
        int g = (tid & 7) ^ (row & 7);
        int lrow = m0 + row;
        int grow = off + ((lrow < cnt) ? lrow : (cnt - 1));
        aSrc[i] = H + (size_t)grow * FF + g * 8;
        bSrc[i] = w2t + (size_t)e * DIM * FF + (size_t)(n0 + row) * FF + g * 8;
    }
    int ldsOff = wid * 512;

    constexpr int NKT = FF / BK;  // 64
#pragma unroll 1
    for (int kt = 0; kt < NKT; ++kt) {
        STAGE(kt);
        __syncthreads();
        COMPUTE();
        __syncthreads();
    }

#pragma unroll
    for (int mi = 0; mi < 4; mi++) {
#pragma unroll
        for (int r = 0; r < 4; r++) {
            int lrow = m0 + wr * 64 + mi * 16 + ((lane >> 4) << 2) + r;
            if (lrow >= cnt) continue;
            int rv = rows[off + lrow];
            float wgt = roww[off + lrow];
            float* op = out + (size_t)(rv >> 1) * DIM + n0 + wc * 64;
#pragma unroll
            for (int nj = 0; nj < 4; nj++)
                atomicAdd(&op[nj * 16 + (lane & 15)], wgt * acc[mi][nj][r]);
        }
    }
}

extern "C" void kernel_launch(void* const* d_in, const int* in_sizes, int n_in,
                              void* d_out, int out_size, void* d_ws, size_t ws_size,
                              hipStream_t stream) {
    const float* x  = (const float*)d_in[0];
    const float* Wr = (const float*)d_in[1];
    const float* W1 = (const float*)d_in[2];
    const float* W2 = (const float*)d_in[3];
    float* out = (float*)d_out;

    char* w = (char*)d_ws;
    size_t o = 0;
    auto carve = [&](size_t bytes) -> void* {
        void* p = w + o;
        o = (o + bytes + 255) & ~(size_t)255;
        return p;
    };
    int*   counts = (int*)carve(NE * 4);
    int*   offs   = (int*)carve(NE * 4);
    int*   cursor = (int*)carve(NE * 4);
    int*   tblE   = (int*)carve(MAXMB * 4);
    int*   tblM   = (int*)carve(MAXMB * 4);
    int*   nmb    = (int*)carve(4);
    int*   topi   = (int*)carve((size_t)NT * 2 * 4);
    float* topw   = (float*)carve((size_t)NT * 2 * 4);
    int*   rows   = (int*)carve((size_t)NT * 2 * 4);
    float* roww   = (float*)carve((size_t)NT * 2 * 4);
    u16*   xbf    = (u16*)carve((size_t)NT * DIM * 2);
    u16*   w1t    = (u16*)carve((size_t)NE * DIM * FF * 2);
    u16*   w2t    = (u16*)carve((size_t)NE * DIM * FF * 2);
    u16*   Hbuf   = (u16*)carve((size_t)NT * 2 * FF * 2);
    (void)ws_size; (void)in_sizes; (void)n_in; (void)out_size;

    hipMemsetAsync(counts, 0, NE * 4, stream);
    hipMemsetAsync(d_out, 0, (size_t)NT * DIM * 4, stream);

    k_router<<<NT / 4, 256, 0, stream>>>(x, Wr, topi, topw, counts);
    k_prefix<<<1, 64, 0, stream>>>(counts, offs, cursor, tblE, tblM, nmb);
    k_build<<<NT / 256, 256, 0, stream>>>(topi, topw, cursor, rows, roww);
    k_cvt<<<(NT * DIM / 8) / 256, 256, 0, stream>>>(x, xbf, NT * DIM);
    {
        dim3 g(FF / 64, DIM / 64, NE);
        k_tcvt<<<g, 256, 0, stream>>>(W1, w1t, DIM, FF);
    }
    {
        dim3 g(DIM / 64, FF / 64, NE);
        k_tcvt<<<g, 256, 0, stream>>>(W2, w2t, FF, DIM);
    }
    k_gemm1<<<G1X, 256, 0, stream>>>(xbf, w1t, rows, offs, counts, tblE, tblM, nmb, Hbuf);
    k_gemm2<<<G2X, 256, 0, stream>>>(Hbuf, w2t, rows, roww, offs, counts, tblE, tblM, nmb, out);
}